// Round 10
// baseline (348.796 us; speedup 1.0000x reference)
//
#include <hip/hip_runtime.h>

typedef unsigned short u16;
typedef unsigned int u32;

#define B_ 2
#define T_ 2048
#define D_ 2048
#define N_ 16
#define H_ 128
#define F_ 64
// 1/sqrt(128) * log2(e)  -- log2e folded so softmax uses v_exp_f32 (2^x) directly
#define QSCALE 0.12751743226f

typedef __attribute__((ext_vector_type(8))) __bf16 bf16x8;
typedef __attribute__((ext_vector_type(8))) short s16x8;
typedef __attribute__((ext_vector_type(4))) float f32x4;
typedef __attribute__((ext_vector_type(4))) u16 u16x4;
typedef __attribute__((ext_vector_type(4))) u32 u32x4;

__device__ inline u16 f2bf(float f) {
    union { float f; u32 u; } v; v.f = f;
    u32 u = v.u;
    u32 r = (u + 0x7FFFu + ((u >> 16) & 1u)) >> 16;
    return (u16)r;
}
__device__ inline float bf2f(u16 h) {
    union { u32 u; float f; } v; v.u = ((u32)h) << 16;
    return v.f;
}
__device__ inline bf16x8 ld8(const u16* p) {
    s16x8 r = *reinterpret_cast<const s16x8*>(p);
    return __builtin_bit_cast(bf16x8, r);
}
__device__ inline f32x4 mfma16(bf16x8 a, bf16x8 b, f32x4 c) {
    return __builtin_amdgcn_mfma_f32_16x16x32_bf16(a, b, c, 0, 0, 0);
}
__device__ inline void gload_lds16(const u16* g, u16* l) {
    __builtin_amdgcn_global_load_lds(
        (const __attribute__((address_space(1))) void*)g,
        (__attribute__((address_space(3))) void*)l, 16, 0, 0);
}
__device__ inline float exp2fast(float x) {
    float r;
    asm("v_exp_f32 %0, %1" : "=v"(r) : "v"(x));
    return r;
}
__device__ inline u32 cvtpk(float lo, float hi) {
    u32 r;
    asm("v_cvt_pk_bf16_f32 %0, %1, %2" : "=v"(r) : "v"(lo), "v"(hi));
    return r;
}

// ---------------- convert f32 -> bf16 (straight) ----------------
__global__ __launch_bounds__(256) void cvt_bf16(const float* __restrict__ in,
                                                u16* __restrict__ out, int n) {
    int i = (blockIdx.x * 256 + threadIdx.x) * 8;
    if (i >= n) return;
    float4 a = *reinterpret_cast<const float4*>(in + i);
    float4 b = *reinterpret_cast<const float4*>(in + i + 4);
    s16x8 o;
    o[0] = (short)f2bf(a.x); o[1] = (short)f2bf(a.y);
    o[2] = (short)f2bf(a.z); o[3] = (short)f2bf(a.w);
    o[4] = (short)f2bf(b.x); o[5] = (short)f2bf(b.y);
    o[6] = (short)f2bf(b.z); o[7] = (short)f2bf(b.w);
    *reinterpret_cast<s16x8*>(out + i) = o;
}

// ---------------- transpose+convert: in[K][Nc] f32 -> out[Nc][K] bf16 ----------------
__global__ __launch_bounds__(256) void transpose_cvt(const float* __restrict__ in,
                                                     u16* __restrict__ out,
                                                     int K, int Nc) {
    __shared__ float tile[64][65];
    int n0 = blockIdx.x * 64, k0 = blockIdx.y * 64;
    int tid = threadIdx.x;
    int rr = tid >> 4;
    int cc = (tid & 15) * 4;
#pragma unroll
    for (int it = 0; it < 4; ++it) {
        int kk = it * 16 + rr;
        float4 v = *reinterpret_cast<const float4*>(in + (size_t)(k0 + kk) * Nc + n0 + cc);
        tile[kk][cc] = v.x; tile[kk][cc + 1] = v.y; tile[kk][cc + 2] = v.z; tile[kk][cc + 3] = v.w;
    }
    __syncthreads();
#pragma unroll
    for (int it = 0; it < 4; ++it) {
        int nn = it * 16 + rr;
        u16x4 o;
#pragma unroll
        for (int j = 0; j < 4; ++j) o[j] = f2bf(tile[cc + j][nn]);
        *reinterpret_cast<u16x4*>(out + (size_t)(n0 + nn) * K + k0 + cc) = o;
    }
}

#define BM 128
#define BN 128
#define BKg 32

// ---------------- QKV GEMM with fused Q-scale / K-rope epilogue ----------------
// Identical K-loop to gemm_bt (proven). Epilogue: each 128-col tile == one head;
// block-uniform branch Q / K / V:
//   Q: qs[hn][t][h] = acc*QSCALE        K: kr[hn][t][h] = rope(acc) via shfl_xor(1)
//   V: vb[row][col] = acc (raw; V-rope+transpose in rope_v)
__global__ __launch_bounds__(256) void gemm_qkv(const u16* __restrict__ A,
                                                const u16* __restrict__ Bt,
                                                u16* __restrict__ qs,
                                                u16* __restrict__ kr,
                                                u16* __restrict__ vb,
                                                const float* __restrict__ cosT,
                                                const float* __restrict__ sinT) {
    __shared__ __align__(16) u16 As[2][BM * BKg];
    __shared__ __align__(16) u16 Bs[2][BM * BKg];
    const int tid = threadIdx.x;
    const int wave = tid >> 6, lane = tid & 63;
    const int K = D_, Nn = 3 * D_;

    const int NW = (Nn >> 7) >> 3;
    const int bid = blockIdx.x;
    const int xcd = bid & 7, idx = bid >> 3;
    const int nloc = idx % NW, mloc = idx / NW;
    const int m0 = mloc * BM, n0 = (xcd * NW + nloc) * BN;

    const int lrow = lane >> 2, lcol = (lane & 3) * 8;
    const int wr = (wave >> 1) * 64, wc = (wave & 1) * 64;
    const int g = lane >> 4, c0 = lane & 15;

    f32x4 acc[4][4] = {};

    const int NT = K / BKg;

    auto stage = [&](int buf, int kt) {
        const int k0 = kt * BKg;
#pragma unroll
        for (int j = 0; j < 2; ++j) {
            const int c = wave + j * 4;
            gload_lds16(A + (size_t)(m0 + c * 16 + lrow) * K + k0 + lcol, &As[buf][c * 512]);
            gload_lds16(Bt + (size_t)(n0 + c * 16 + lrow) * K + k0 + lcol, &Bs[buf][c * 512]);
        }
    };

    stage(0, 0);
    __syncthreads();

    for (int t = 0; t < NT; ++t) {
        const int cur = t & 1;
        if (t + 1 < NT) stage(cur ^ 1, t + 1);
        bf16x8 af[4], bfr[4];
#pragma unroll
        for (int i = 0; i < 4; ++i) {
            af[i]  = ld8(&As[cur][(wr + i * 16 + c0) * BKg + g * 8]);
            bfr[i] = ld8(&Bs[cur][(wc + i * 16 + c0) * BKg + g * 8]);
        }
#pragma unroll
        for (int i = 0; i < 4; ++i)
#pragma unroll
            for (int j = 0; j < 4; ++j)
                acc[i][j] = mfma16(af[i], bfr[j], acc[i][j]);
        __syncthreads();
    }

    // ---- fused epilogue (branch uniform per block: n0 aligned to 128, heads=128) ----
    if (n0 < D_) {
        // Q: scaled scatter to qs[hn][t][h]
#pragma unroll
        for (int i = 0; i < 4; ++i)
#pragma unroll
            for (int j = 0; j < 4; ++j) {
                int col = n0 + wc + j * 16 + c0;
                int hn0 = col >> 7, h = col & 127;
#pragma unroll
                for (int r = 0; r < 4; ++r) {
                    int row = m0 + wr + i * 16 + g * 4 + r;
                    int bb = row >> 11, t = row & (T_ - 1);
                    qs[((size_t)(bb * 16 + hn0) * T_ + t) * H_ + h] = f2bf(acc[i][j][r] * QSCALE);
                }
            }
    } else if (n0 < 2 * D_) {
        // K: rope + scatter to kr[hn][t][h]
#pragma unroll
        for (int i = 0; i < 4; ++i)
#pragma unroll
            for (int j = 0; j < 4; ++j) {
                int colj = (n0 - D_) + wc + j * 16 + c0;
                int hn0 = colj >> 7, h = colj & 127, f = (h >> 1);
#pragma unroll
                for (int r = 0; r < 4; ++r) {
                    int row = m0 + wr + i * 16 + g * 4 + r;
                    int bb = row >> 11, t = row & (T_ - 1);
                    float v = acc[i][j][r];
                    float p = __shfl_xor(v, 1);
                    float cth = cosT[t * F_ + f], sth = sinT[t * F_ + f];
                    float outv = (c0 & 1) ? (p * sth + v * cth) : (v * cth - p * sth);
                    kr[((size_t)(bb * 16 + hn0) * T_ + t) * H_ + h] = f2bf(outv);
                }
            }
    } else {
        // V: raw compact write, rope_v handles rope+transpose
#pragma unroll
        for (int i = 0; i < 4; ++i)
#pragma unroll
            for (int j = 0; j < 4; ++j) {
                int colv = (n0 - 2 * D_) + wc + j * 16 + c0;
#pragma unroll
                for (int r = 0; r < 4; ++r) {
                    int row = m0 + wr + i * 16 + g * 4 + r;
                    vb[(size_t)row * D_ + colv] = f2bf(acc[i][j][r]);
                }
            }
    }
}

// ---------------- 128x128 GEMM (final projection) ----------------
__global__ __launch_bounds__(256) void gemm_bt(const u16* __restrict__ A,
                                               const u16* __restrict__ Bt,
                                               float* __restrict__ Cf,
                                               int M, int Nn, int K) {
    __shared__ __align__(16) u16 As[2][BM * BKg];
    __shared__ __align__(16) u16 Bs[2][BM * BKg];
    const int tid = threadIdx.x;
    const int wave = tid >> 6, lane = tid & 63;

    const int NW = (Nn >> 7) >> 3;
    const int bid = blockIdx.x;
    const int xcd = bid & 7, idx = bid >> 3;
    const int nloc = idx % NW, mloc = idx / NW;
    const int m0 = mloc * BM, n0 = (xcd * NW + nloc) * BN;

    const int lrow = lane >> 2, lcol = (lane & 3) * 8;
    const int wr = (wave >> 1) * 64, wc = (wave & 1) * 64;
    const int g = lane >> 4, c0 = lane & 15;

    f32x4 acc[4][4] = {};

    const int NT = K / BKg;

    auto stage = [&](int buf, int kt) {
        const int k0 = kt * BKg;
#pragma unroll
        for (int j = 0; j < 2; ++j) {
            const int c = wave + j * 4;
            gload_lds16(A + (size_t)(m0 + c * 16 + lrow) * K + k0 + lcol, &As[buf][c * 512]);
            gload_lds16(Bt + (size_t)(n0 + c * 16 + lrow) * K + k0 + lcol, &Bs[buf][c * 512]);
        }
    };

    stage(0, 0);
    __syncthreads();

    for (int t = 0; t < NT; ++t) {
        const int cur = t & 1;
        if (t + 1 < NT) stage(cur ^ 1, t + 1);
        bf16x8 af[4], bfr[4];
#pragma unroll
        for (int i = 0; i < 4; ++i) {
            af[i]  = ld8(&As[cur][(wr + i * 16 + c0) * BKg + g * 8]);
            bfr[i] = ld8(&Bs[cur][(wc + i * 16 + c0) * BKg + g * 8]);
        }
#pragma unroll
        for (int i = 0; i < 4; ++i)
#pragma unroll
            for (int j = 0; j < 4; ++j)
                acc[i][j] = mfma16(af[i], bfr[j], acc[i][j]);
        __syncthreads();
    }

#pragma unroll
    for (int i = 0; i < 4; ++i)
#pragma unroll
        for (int j = 0; j < 4; ++j)
#pragma unroll
            for (int r = 0; r < 4; ++r) {
                int row = m0 + wr + i * 16 + g * 4 + r;
                int col = n0 + wc + j * 16 + c0;
                Cf[(size_t)row * Nn + col] = acc[i][j][r];
            }
}

// ---------------- V rope + head-split + transpose (vb [B*T][D] -> vt [BN][H][T]) ----------------
__global__ __launch_bounds__(256) void rope_v(const u16* __restrict__ vb,
                                              const float* __restrict__ cosT,
                                              const float* __restrict__ sinT,
                                              u16* __restrict__ vt) {
    __shared__ u16 vtile[64][129];
    int bi = blockIdx.x;
    int hn = bi >> 5;
    int tt = bi & 31;
    int b = hn >> 4, n = hn & 15;
    int t0 = tt * 64;
    int tid = threadIdx.x;
    int tl = tid >> 2;
    int h0 = (tid & 3) * 32;
    int t = t0 + tl;
    const u16* row = vb + ((size_t)(b * T_ + t)) * D_ + n * H_;

    float cbuf[16], sbuf[16];
    const float* cr = cosT + (size_t)t * F_ + h0 / 2;
    const float* sr = sinT + (size_t)t * F_ + h0 / 2;
#pragma unroll
    for (int u = 0; u < 4; ++u) {
        float4 c4 = *reinterpret_cast<const float4*>(cr + u * 4);
        float4 s4 = *reinterpret_cast<const float4*>(sr + u * 4);
        cbuf[u * 4 + 0] = c4.x; cbuf[u * 4 + 1] = c4.y; cbuf[u * 4 + 2] = c4.z; cbuf[u * 4 + 3] = c4.w;
        sbuf[u * 4 + 0] = s4.x; sbuf[u * 4 + 1] = s4.y; sbuf[u * 4 + 2] = s4.z; sbuf[u * 4 + 3] = s4.w;
    }

#pragma unroll
    for (int u = 0; u < 4; ++u) {
        s16x8 raw = *reinterpret_cast<const s16x8*>(row + h0 + u * 8);
#pragma unroll
        for (int p = 0; p < 4; ++p) {
            float xr = bf2f((u16)raw[2 * p]), xi = bf2f((u16)raw[2 * p + 1]);
            float cc = cbuf[u * 4 + p], ss = sbuf[u * 4 + p];
            vtile[tl][h0 + u * 8 + 2 * p]     = f2bf(xr * cc - xi * ss);
            vtile[tl][h0 + u * 8 + 2 * p + 1] = f2bf(xr * ss + xi * cc);
        }
    }
    __syncthreads();

    int hrow = tid >> 1;
    int th = (tid & 1) * 32;
    u16 tmp[32];
#pragma unroll
    for (int i = 0; i < 32; ++i) tmp[i] = vtile[th + i][hrow];
    u16* dst = vt + ((size_t)(hn * H_ + hrow)) * T_ + t0 + th;
#pragma unroll
    for (int u = 0; u < 4; ++u) {
        s16x8 o;
#pragma unroll
        for (int e = 0; e < 8; ++e) o[e] = (short)tmp[u * 8 + e];
        *reinterpret_cast<s16x8*>(dst + u * 8) = o;
    }
}

// ---------------- flash attention (causal), swapped-operand softmax ----------------
// EXACT round-3 structure (best measured): K+V double-buffered global_load_lds
// staged at iteration top, one __syncthreads per iteration.
__global__ __launch_bounds__(256, 2) void attn_fwd(const u16* __restrict__ qs,
                                                   const u16* __restrict__ kr,
                                                   const u16* __restrict__ vt,
                                                   u16* __restrict__ ob) {
    __shared__ __align__(16) u16 Ks[2][8192];
    __shared__ __align__(16) u16 Vs[2][8192];

    const int wave = threadIdx.x >> 6, lane = threadIdx.x & 63;
    const int g = lane >> 4, c0 = lane & 15;

    const int wg = blockIdx.x;
    const int orig = (wg & 7) * 64 + (wg >> 3);
    const int hn = orig >> 4;
    const int qt = orig & 15;
    const int bq0 = (15 - qt) * 128;

    const u16* qh = qs + (size_t)hn * T_ * H_;
    const u16* kh = kr + (size_t)hn * T_ * H_;
    const u16* vh = vt + (size_t)hn * H_ * T_;

    const int q0[2] = { bq0 + wave * 16, bq0 + 64 + wave * 16 };

    bf16x8 qf[2][4];
#pragma unroll
    for (int i = 0; i < 2; ++i)
#pragma unroll
        for (int kf = 0; kf < 4; ++kf)
            qf[i][kf] = ld8(qh + (size_t)(q0[i] + c0) * H_ + kf * 32 + g * 8);

    f32x4 o[2][8] = {};
    float m[2] = { -1e30f, -1e30f };
    float l[2] = { 0.0f, 0.0f };

    const int nt = bq0 / 64 + 2;

    auto stage = [&](int buf, int t) {
        const int kv0 = t * 64;
#pragma unroll
        for (int j = 0; j < 4; ++j) {
            int ra = wave * 16 + j * 4 + (lane >> 4);
            int ca = ((lane & 15) * 8) ^ ((ra & 7) << 3);
            gload_lds16(kh + (size_t)(kv0 + ra) * H_ + ca, &Ks[buf][wave * 2048 + j * 512]);
            int rv = wave * 32 + j * 8 + (lane >> 3);
            int cv = ((lane & 7) * 8) ^ ((rv & 7) << 3);
            gload_lds16(vh + (size_t)rv * T_ + kv0 + cv, &Vs[buf][wave * 2048 + j * 512]);
        }
    };

    stage(0, 0);
    __syncthreads();

    const int srcA = ((g & 1) * 2) * 16 + c0;
    const int srcB = srcA + 16;
    const int sel  = g >> 1;

    for (int t = 0; t < nt; ++t) {
        const int cur = t & 1;
        const int kv0 = t * 64;
        if (t + 1 < nt) stage(cur ^ 1, t + 1);

        const bool a0 = kv0 < q0[0] + 16;
        const bool a1 = kv0 < q0[1] + 16;

        f32x4 s[2][4] = {};
        __builtin_amdgcn_s_setprio(1);
#pragma unroll
        for (int cc = 0; cc < 4; ++cc) {
            const int krow = cc * 16 + c0;
#pragma unroll
            for (int kf = 0; kf < 4; ++kf) {
                bf16x8 kfr = ld8(&Ks[cur][krow * 128 + ((kf * 32 + g * 8) ^ ((krow & 7) << 3))]);
                if (a0) s[0][cc] = mfma16(kfr, qf[0][kf], s[0][cc]);
                if (a1) s[1][cc] = mfma16(kfr, qf[1][kf], s[1][cc]);
            }
        }
        __builtin_amdgcn_s_setprio(0);

        bf16x8 pb[2][2];
#pragma unroll
        for (int i = 0; i < 2; ++i) {
            const bool act = i ? a1 : a0;
            if (!act) continue;
            const int qrow = q0[i] + c0;
            if (kv0 + 63 > q0[i]) {
#pragma unroll
                for (int cc = 0; cc < 4; ++cc) {
                    int kloc = kv0 + cc * 16 + g * 4;
#pragma unroll
                    for (int r = 0; r < 4; ++r)
                        if (kloc + r > qrow) s[i][cc][r] = -1e30f;
                }
            }
            float pmax = s[i][0][0];
#pragma unroll
            for (int cc = 0; cc < 4; ++cc)
#pragma unroll
                for (int r = 0; r < 4; ++r) pmax = fmaxf(pmax, s[i][cc][r]);
            if (!__all(pmax <= m[i] + 8.0f)) {
                pmax = fmaxf(pmax, __shfl_xor(pmax, 16));
                pmax = fmaxf(pmax, __shfl_xor(pmax, 32));
                float mn = fmaxf(m[i], pmax);
                float al = exp2fast(m[i] - mn);
                m[i] = mn;
                l[i] *= al;
#pragma unroll
                for (int hf = 0; hf < 8; ++hf)
#pragma unroll
                    for (int r = 0; r < 4; ++r) o[i][hf][r] *= al;
            }
            u32 w[4][2];
#pragma unroll
            for (int cc = 0; cc < 4; ++cc) {
                float p0 = exp2fast(s[i][cc][0] - m[i]);
                float p1 = exp2fast(s[i][cc][1] - m[i]);
                float p2 = exp2fast(s[i][cc][2] - m[i]);
                float p3 = exp2fast(s[i][cc][3] - m[i]);
                l[i] += (p0 + p1) + (p2 + p3);
                w[cc][0] = cvtpk(p0, p1);
                w[cc][1] = cvtpk(p2, p3);
            }
#pragma unroll
            for (int ks2 = 0; ks2 < 2; ++ks2) {
                u32 r00 = __shfl(w[ks2 * 2 + 0][0], srcA);
                u32 r01 = __shfl(w[ks2 * 2 + 0][1], srcA);
                u32 r02 = __shfl(w[ks2 * 2 + 0][0], srcB);
                u32 r03 = __shfl(w[ks2 * 2 + 0][1], srcB);
                u32 r10 = __shfl(w[ks2 * 2 + 1][0], srcA);
                u32 r11 = __shfl(w[ks2 * 2 + 1][1], srcA);
                u32 r12 = __shfl(w[ks2 * 2 + 1][0], srcB);
                u32 r13 = __shfl(w[ks2 * 2 + 1][1], srcB);
                u32x4 wv;
                wv[0] = sel ? r10 : r00;
                wv[1] = sel ? r11 : r01;
                wv[2] = sel ? r12 : r02;
                wv[3] = sel ? r13 : r03;
                pb[i][ks2] = __builtin_bit_cast(bf16x8, wv);
            }
        }

        __builtin_amdgcn_s_setprio(1);
#pragma unroll
        for (int hf = 0; hf < 8; ++hf) {
            const int vrow = hf * 16 + c0;
#pragma unroll
            for (int ks2 = 0; ks2 < 2; ++ks2) {
                bf16x8 vfr = ld8(&Vs[cur][vrow * 64 + ((ks2 * 32 + g * 8) ^ ((vrow & 7) << 3))]);
                if (a0) o[0][hf] = mfma16(vfr, pb[0][ks2], o[0][hf]);
                if (a1) o[1][hf] = mfma16(vfr, pb[1][ks2], o[1][hf]);
            }
        }
        __builtin_amdgcn_s_setprio(0);
        __syncthreads();
    }

    const int bb = hn >> 4, nn = hn & 15;
#pragma unroll
    for (int i = 0; i < 2; ++i) {
        float lt = l[i] + __shfl_xor(l[i], 16);
        lt += __shfl_xor(lt, 32);
        float inv = 1.0f / lt;
        const size_t rowoff = ((size_t)(bb * T_ + q0[i] + c0)) * D_ + nn * H_ + g * 4;
#pragma unroll
        for (int hf = 0; hf < 8; ++hf) {
            u16x4 pk;
#pragma unroll
            for (int r = 0; r < 4; ++r) pk[r] = f2bf(o[i][hf][r] * inv);
            *reinterpret_cast<u16x4*>(ob + rowoff + hf * 16) = pk;
        }
    }
}

// ---------------- launch ----------------
extern "C" void kernel_launch(void* const* d_in, const int* in_sizes, int n_in,
                              void* d_out, int out_size, void* d_ws, size_t ws_size,
                              hipStream_t stream) {
    const float* x      = (const float*)d_in[0];
    const float* cosT   = (const float*)d_in[2];
    const float* sinT   = (const float*)d_in[3];
    const float* w_attn = (const float*)d_in[4];
    const float* w_out  = (const float*)d_in[5];
    float* out = (float*)d_out;

    char* ws = (char*)d_ws;
    u16* xb  = (u16*)(ws + 0);                  // x bf16 [4096][2048]
    u16* wat = (u16*)(ws + 16777216);           // w_attn^T bf16
    u16* wot = (u16*)(ws + 41943040);           // w_out^T bf16
    u16* vb  = (u16*)(ws + 50331648);           // V raw bf16 [4096][2048]
    u16* qsb = (u16*)(ws + 100663296);          // q scaled  [32][2048][128]
    u16* krb = (u16*)(ws + 117440512);          // k rope    [32][2048][128]
    u16* vtb = (u16*)(ws + 134217728);          // v rope transposed [32][128][2048]
    u16* obf = (u16*)(ws + 0);                  // attn out bf16 (reuses xb)

    cvt_bf16<<<(B_ * T_ * D_) / (256 * 8), 256, 0, stream>>>(x, xb, B_ * T_ * D_);
    transpose_cvt<<<dim3(3 * D_ / 64, D_ / 64), 256, 0, stream>>>(w_attn, wat, D_, 3 * D_);
    transpose_cvt<<<dim3(D_ / 64, D_ / 64), 256, 0, stream>>>(w_out, wot, D_, D_);
    // QKV projection with fused Q-scale/K-rope epilogue
    gemm_qkv<<<dim3((3 * D_ / BN) * (B_ * T_ / BM)), 256, 0, stream>>>(
        xb, wat, qsb, krb, vb, cosT, sinT);
    rope_v<<<B_ * N_ * (T_ / 64), 256, 0, stream>>>(vb, cosT, sinT, vtb);
    attn_fwd<<<B_ * N_ * (T_ / 128), 256, 0, stream>>>(qsb, krb, vtb, obf);
    gemm_bt<<<dim3((D_ / BN) * (B_ * T_ / BM)), 256, 0, stream>>>(obf, wot, out,
                                                                  B_ * T_, D_, D_);
}

// Round 11
// 315.272 us; speedup vs baseline: 1.1063x; 1.1063x over previous
//
#include <hip/hip_runtime.h>

typedef unsigned short u16;
typedef unsigned int u32;

#define B_ 2
#define T_ 2048
#define D_ 2048
#define N_ 16
#define H_ 128
#define F_ 64
// 1/sqrt(128) * log2(e)  -- log2e folded so softmax uses v_exp_f32 (2^x) directly
#define QSCALE 0.12751743226f

typedef __attribute__((ext_vector_type(8))) __bf16 bf16x8;
typedef __attribute__((ext_vector_type(8))) short s16x8;
typedef __attribute__((ext_vector_type(4))) float f32x4;
typedef __attribute__((ext_vector_type(4))) u16 u16x4;
typedef __attribute__((ext_vector_type(4))) u32 u32x4;

__device__ inline u16 f2bf(float f) {
    union { float f; u32 u; } v; v.f = f;
    u32 u = v.u;
    u32 r = (u + 0x7FFFu + ((u >> 16) & 1u)) >> 16;
    return (u16)r;
}
__device__ inline float bf2f(u16 h) {
    union { u32 u; float f; } v; v.u = ((u32)h) << 16;
    return v.f;
}
__device__ inline bf16x8 ld8(const u16* p) {
    s16x8 r = *reinterpret_cast<const s16x8*>(p);
    return __builtin_bit_cast(bf16x8, r);
}
__device__ inline f32x4 mfma16(bf16x8 a, bf16x8 b, f32x4 c) {
    return __builtin_amdgcn_mfma_f32_16x16x32_bf16(a, b, c, 0, 0, 0);
}
__device__ inline void gload_lds16(const u16* g, u16* l) {
    __builtin_amdgcn_global_load_lds(
        (const __attribute__((address_space(1))) void*)g,
        (__attribute__((address_space(3))) void*)l, 16, 0, 0);
}
__device__ inline float exp2fast(float x) {
    float r;
    asm("v_exp_f32 %0, %1" : "=v"(r) : "v"(x));
    return r;
}
__device__ inline u32 cvtpk(float lo, float hi) {
    u32 r;
    asm("v_cvt_pk_bf16_f32 %0, %1, %2" : "=v"(r) : "v"(lo), "v"(hi));
    return r;
}

// ---------------- convert f32 -> bf16 (straight) ----------------
__global__ __launch_bounds__(256) void cvt_bf16(const float* __restrict__ in,
                                                u16* __restrict__ out, int n) {
    int i = (blockIdx.x * 256 + threadIdx.x) * 8;
    if (i >= n) return;
    float4 a = *reinterpret_cast<const float4*>(in + i);
    float4 b = *reinterpret_cast<const float4*>(in + i + 4);
    s16x8 o;
    o[0] = (short)f2bf(a.x); o[1] = (short)f2bf(a.y);
    o[2] = (short)f2bf(a.z); o[3] = (short)f2bf(a.w);
    o[4] = (short)f2bf(b.x); o[5] = (short)f2bf(b.y);
    o[6] = (short)f2bf(b.z); o[7] = (short)f2bf(b.w);
    *reinterpret_cast<s16x8*>(out + i) = o;
}

// ---------------- transpose+convert: in[K][Nc] f32 -> out[Nc][K] bf16 ----------------
__global__ __launch_bounds__(256) void transpose_cvt(const float* __restrict__ in,
                                                     u16* __restrict__ out,
                                                     int K, int Nc) {
    __shared__ float tile[64][65];
    int n0 = blockIdx.x * 64, k0 = blockIdx.y * 64;
    int tid = threadIdx.x;
    int rr = tid >> 4;
    int cc = (tid & 15) * 4;
#pragma unroll
    for (int it = 0; it < 4; ++it) {
        int kk = it * 16 + rr;
        float4 v = *reinterpret_cast<const float4*>(in + (size_t)(k0 + kk) * Nc + n0 + cc);
        tile[kk][cc] = v.x; tile[kk][cc + 1] = v.y; tile[kk][cc + 2] = v.z; tile[kk][cc + 3] = v.w;
    }
    __syncthreads();
#pragma unroll
    for (int it = 0; it < 4; ++it) {
        int nn = it * 16 + rr;
        u16x4 o;
#pragma unroll
        for (int j = 0; j < 4; ++j) o[j] = f2bf(tile[cc + j][nn]);
        *reinterpret_cast<u16x4*>(out + (size_t)(n0 + nn) * K + k0 + cc) = o;
    }
}

// ---------------- 128x128 GEMM (both projections), XCD-rect swizzle ----------------
#define BM 128
#define BN 128
#define BKg 32

__global__ __launch_bounds__(256) void gemm_bt(const u16* __restrict__ A,
                                               const u16* __restrict__ Bt,
                                               u16* __restrict__ Cb,
                                               float* __restrict__ Cf,
                                               int M, int Nn, int K, int out_f32) {
    __shared__ __align__(16) u16 As[2][BM * BKg];
    __shared__ __align__(16) u16 Bs[2][BM * BKg];
    const int tid = threadIdx.x;
    const int wave = tid >> 6, lane = tid & 63;

    const int NW = (Nn >> 7) >> 3;          // n-tiles per XCD
    const int bid = blockIdx.x;
    const int xcd = bid & 7, idx = bid >> 3;
    const int nloc = idx % NW, mloc = idx / NW;
    const int m0 = mloc * BM, n0 = (xcd * NW + nloc) * BN;

    const int lrow = lane >> 2, lcol = (lane & 3) * 8;
    const int wr = (wave >> 1) * 64, wc = (wave & 1) * 64;
    const int g = lane >> 4, c0 = lane & 15;

    f32x4 acc[4][4] = {};

    const int NT = K / BKg;

    auto stage = [&](int buf, int kt) {
        const int k0 = kt * BKg;
#pragma unroll
        for (int j = 0; j < 2; ++j) {
            const int c = wave + j * 4;
            gload_lds16(A + (size_t)(m0 + c * 16 + lrow) * K + k0 + lcol, &As[buf][c * 512]);
            gload_lds16(Bt + (size_t)(n0 + c * 16 + lrow) * K + k0 + lcol, &Bs[buf][c * 512]);
        }
    };

    stage(0, 0);
    __syncthreads();

    for (int t = 0; t < NT; ++t) {
        const int cur = t & 1;
        if (t + 1 < NT) stage(cur ^ 1, t + 1);
        bf16x8 af[4], bfr[4];
#pragma unroll
        for (int i = 0; i < 4; ++i) {
            af[i]  = ld8(&As[cur][(wr + i * 16 + c0) * BKg + g * 8]);
            bfr[i] = ld8(&Bs[cur][(wc + i * 16 + c0) * BKg + g * 8]);
        }
#pragma unroll
        for (int i = 0; i < 4; ++i)
#pragma unroll
            for (int j = 0; j < 4; ++j)
                acc[i][j] = mfma16(af[i], bfr[j], acc[i][j]);
        __syncthreads();
    }

#pragma unroll
    for (int i = 0; i < 4; ++i)
#pragma unroll
        for (int j = 0; j < 4; ++j)
#pragma unroll
            for (int r = 0; r < 4; ++r) {
                int row = m0 + wr + i * 16 + g * 4 + r;
                int col = n0 + wc + j * 16 + c0;
                float v = acc[i][j][r];
                if (out_f32) Cf[(size_t)row * Nn + col] = v;
                else         Cb[(size_t)row * Nn + col] = f2bf(v);
            }
}

// ---------------- RoPE + head-split + V-transpose ----------------
__global__ __launch_bounds__(256) void rope_split(const u16* __restrict__ qkv,
                                                  const float* __restrict__ cosT,
                                                  const float* __restrict__ sinT,
                                                  u16* __restrict__ qs,
                                                  u16* __restrict__ kr,
                                                  u16* __restrict__ vt) {
    __shared__ u16 vtile[64][129];
    int bi = blockIdx.x;
    int hn = bi >> 5;
    int tt = bi & 31;
    int b = hn >> 4, n = hn & 15;
    int t0 = tt * 64;
    int tid = threadIdx.x;
    int tl = tid >> 2;
    int h0 = (tid & 3) * 32;
    int t = t0 + tl;
    const u16* row = qkv + ((size_t)(b * T_ + t)) * (3 * D_);

#pragma unroll
    for (int u = 0; u < 4; ++u) {
        s16x8 raw = *reinterpret_cast<const s16x8*>(row + n * H_ + h0 + u * 8);
        s16x8 o;
#pragma unroll
        for (int e = 0; e < 8; ++e) o[e] = (short)f2bf(bf2f((u16)raw[e]) * QSCALE);
        *reinterpret_cast<s16x8*>(qs + ((size_t)hn * T_ + t) * H_ + h0 + u * 8) = o;
    }

    float cbuf[16], sbuf[16];
    const float* cr = cosT + (size_t)t * F_ + h0 / 2;
    const float* sr = sinT + (size_t)t * F_ + h0 / 2;
#pragma unroll
    for (int u = 0; u < 4; ++u) {
        float4 c4 = *reinterpret_cast<const float4*>(cr + u * 4);
        float4 s4 = *reinterpret_cast<const float4*>(sr + u * 4);
        cbuf[u * 4 + 0] = c4.x; cbuf[u * 4 + 1] = c4.y; cbuf[u * 4 + 2] = c4.z; cbuf[u * 4 + 3] = c4.w;
        sbuf[u * 4 + 0] = s4.x; sbuf[u * 4 + 1] = s4.y; sbuf[u * 4 + 2] = s4.z; sbuf[u * 4 + 3] = s4.w;
    }

#pragma unroll
    for (int u = 0; u < 4; ++u) {
        s16x8 raw = *reinterpret_cast<const s16x8*>(row + D_ + n * H_ + h0 + u * 8);
        s16x8 o;
#pragma unroll
        for (int p = 0; p < 4; ++p) {
            float xr = bf2f((u16)raw[2 * p]), xi = bf2f((u16)raw[2 * p + 1]);
            float cc = cbuf[u * 4 + p], ss = sbuf[u * 4 + p];
            o[2 * p]     = (short)f2bf(xr * cc - xi * ss);
            o[2 * p + 1] = (short)f2bf(xr * ss + xi * cc);
        }
        *reinterpret_cast<s16x8*>(kr + ((size_t)hn * T_ + t) * H_ + h0 + u * 8) = o;
    }

#pragma unroll
    for (int u = 0; u < 4; ++u) {
        s16x8 raw = *reinterpret_cast<const s16x8*>(row + 2 * D_ + n * H_ + h0 + u * 8);
#pragma unroll
        for (int p = 0; p < 4; ++p) {
            float xr = bf2f((u16)raw[2 * p]), xi = bf2f((u16)raw[2 * p + 1]);
            float cc = cbuf[u * 4 + p], ss = sbuf[u * 4 + p];
            vtile[tl][h0 + u * 8 + 2 * p]     = f2bf(xr * cc - xi * ss);
            vtile[tl][h0 + u * 8 + 2 * p + 1] = f2bf(xr * ss + xi * cc);
        }
    }
    __syncthreads();

    int hrow = tid >> 1;
    int th = (tid & 1) * 32;
    u16 tmp[32];
#pragma unroll
    for (int i = 0; i < 32; ++i) tmp[i] = vtile[th + i][hrow];
    u16* dst = vt + ((size_t)(hn * H_ + hrow)) * T_ + t0 + th;
#pragma unroll
    for (int u = 0; u < 4; ++u) {
        s16x8 o;
#pragma unroll
        for (int e = 0; e < 8; ++e) o[e] = (short)tmp[u * 8 + e];
        *reinterpret_cast<s16x8*>(dst + u * 8) = o;
    }
}

// ---------------- flash attention (causal), swapped-operand softmax ----------------
// Round-3 inner structure (proven). NEW: causal load balancing -- each block's two
// 16-row row-blocks come from complementary 64-row halves (hA = 31-qt long,
// hB = qt short) of the same head, so every block costs ~17-21 iter-equivalents
// instead of 2..32 (worst-CU was ~2x average with exactly 2 blocks/CU resident).
// The existing a0/a1 guards handle the short half's early termination.
__global__ __launch_bounds__(256, 2) void attn_fwd(const u16* __restrict__ qs,
                                                   const u16* __restrict__ kr,
                                                   const u16* __restrict__ vt,
                                                   u16* __restrict__ ob) {
    __shared__ __align__(16) u16 Ks[2][8192];
    __shared__ __align__(16) u16 Vs[2][8192];

    const int wave = threadIdx.x >> 6, lane = threadIdx.x & 63;
    const int g = lane >> 4, c0 = lane & 15;

    const int wg = blockIdx.x;
    const int orig = (wg & 7) * 64 + (wg >> 3);
    const int hn = orig >> 4;
    const int qt = orig & 15;
    const int hA = 31 - qt;      // long 64-row half (dispatched first: qt=0)
    const int hB = qt;           // complementary short half

    const u16* qh = qs + (size_t)hn * T_ * H_;
    const u16* kh = kr + (size_t)hn * T_ * H_;
    const u16* vh = vt + (size_t)hn * H_ * T_;

    const int q0[2] = { hA * 64 + wave * 16, hB * 64 + wave * 16 };

    bf16x8 qf[2][4];
#pragma unroll
    for (int i = 0; i < 2; ++i)
#pragma unroll
        for (int kf = 0; kf < 4; ++kf)
            qf[i][kf] = ld8(qh + (size_t)(q0[i] + c0) * H_ + kf * 32 + g * 8);

    f32x4 o[2][8] = {};
    float m[2] = { -1e30f, -1e30f };
    float l[2] = { 0.0f, 0.0f };

    const int nt = hA + 1;       // kv tiles 0..hA cover the long half's causal range

    auto stage = [&](int buf, int t) {
        const int kv0 = t * 64;
#pragma unroll
        for (int j = 0; j < 4; ++j) {
            int ra = wave * 16 + j * 4 + (lane >> 4);
            int ca = ((lane & 15) * 8) ^ ((ra & 7) << 3);
            gload_lds16(kh + (size_t)(kv0 + ra) * H_ + ca, &Ks[buf][wave * 2048 + j * 512]);
            int rv = wave * 32 + j * 8 + (lane >> 3);
            int cv = ((lane & 7) * 8) ^ ((rv & 7) << 3);
            gload_lds16(vh + (size_t)rv * T_ + kv0 + cv, &Vs[buf][wave * 2048 + j * 512]);
        }
    };

    stage(0, 0);
    __syncthreads();

    const int srcA = ((g & 1) * 2) * 16 + c0;
    const int srcB = srcA + 16;
    const int sel  = g >> 1;

    for (int t = 0; t < nt; ++t) {
        const int cur = t & 1;
        const int kv0 = t * 64;
        if (t + 1 < nt) stage(cur ^ 1, t + 1);

        const bool a0 = kv0 < q0[0] + 16;
        const bool a1 = kv0 < q0[1] + 16;

        f32x4 s[2][4] = {};
        __builtin_amdgcn_s_setprio(1);
#pragma unroll
        for (int cc = 0; cc < 4; ++cc) {
            const int krow = cc * 16 + c0;
#pragma unroll
            for (int kf = 0; kf < 4; ++kf) {
                bf16x8 kfr = ld8(&Ks[cur][krow * 128 + ((kf * 32 + g * 8) ^ ((krow & 7) << 3))]);
                if (a0) s[0][cc] = mfma16(kfr, qf[0][kf], s[0][cc]);
                if (a1) s[1][cc] = mfma16(kfr, qf[1][kf], s[1][cc]);
            }
        }
        __builtin_amdgcn_s_setprio(0);

        bf16x8 pb[2][2];
#pragma unroll
        for (int i = 0; i < 2; ++i) {
            const bool act = i ? a1 : a0;
            if (!act) continue;
            const int qrow = q0[i] + c0;
            if (kv0 + 63 > q0[i]) {
#pragma unroll
                for (int cc = 0; cc < 4; ++cc) {
                    int kloc = kv0 + cc * 16 + g * 4;
#pragma unroll
                    for (int r = 0; r < 4; ++r)
                        if (kloc + r > qrow) s[i][cc][r] = -1e30f;
                }
            }
            float pmax = s[i][0][0];
#pragma unroll
            for (int cc = 0; cc < 4; ++cc)
#pragma unroll
                for (int r = 0; r < 4; ++r) pmax = fmaxf(pmax, s[i][cc][r]);
            if (!__all(pmax <= m[i] + 8.0f)) {
                pmax = fmaxf(pmax, __shfl_xor(pmax, 16));
                pmax = fmaxf(pmax, __shfl_xor(pmax, 32));
                float mn = fmaxf(m[i], pmax);
                float al = exp2fast(m[i] - mn);
                m[i] = mn;
                l[i] *= al;
#pragma unroll
                for (int hf = 0; hf < 8; ++hf)
#pragma unroll
                    for (int r = 0; r < 4; ++r) o[i][hf][r] *= al;
            }
            u32 w[4][2];
#pragma unroll
            for (int cc = 0; cc < 4; ++cc) {
                float p0 = exp2fast(s[i][cc][0] - m[i]);
                float p1 = exp2fast(s[i][cc][1] - m[i]);
                float p2 = exp2fast(s[i][cc][2] - m[i]);
                float p3 = exp2fast(s[i][cc][3] - m[i]);
                l[i] += (p0 + p1) + (p2 + p3);
                w[cc][0] = cvtpk(p0, p1);
                w[cc][1] = cvtpk(p2, p3);
            }
#pragma unroll
            for (int ks2 = 0; ks2 < 2; ++ks2) {
                u32 r00 = __shfl(w[ks2 * 2 + 0][0], srcA);
                u32 r01 = __shfl(w[ks2 * 2 + 0][1], srcA);
                u32 r02 = __shfl(w[ks2 * 2 + 0][0], srcB);
                u32 r03 = __shfl(w[ks2 * 2 + 0][1], srcB);
                u32 r10 = __shfl(w[ks2 * 2 + 1][0], srcA);
                u32 r11 = __shfl(w[ks2 * 2 + 1][1], srcA);
                u32 r12 = __shfl(w[ks2 * 2 + 1][0], srcB);
                u32 r13 = __shfl(w[ks2 * 2 + 1][1], srcB);
                u32x4 wv;
                wv[0] = sel ? r10 : r00;
                wv[1] = sel ? r11 : r01;
                wv[2] = sel ? r12 : r02;
                wv[3] = sel ? r13 : r03;
                pb[i][ks2] = __builtin_bit_cast(bf16x8, wv);
            }
        }

        __builtin_amdgcn_s_setprio(1);
#pragma unroll
        for (int hf = 0; hf < 8; ++hf) {
            const int vrow = hf * 16 + c0;
#pragma unroll
            for (int ks2 = 0; ks2 < 2; ++ks2) {
                bf16x8 vfr = ld8(&Vs[cur][vrow * 64 + ((ks2 * 32 + g * 8) ^ ((vrow & 7) << 3))]);
                if (a0) o[0][hf] = mfma16(vfr, pb[0][ks2], o[0][hf]);
                if (a1) o[1][hf] = mfma16(vfr, pb[1][ks2], o[1][hf]);
            }
        }
        __builtin_amdgcn_s_setprio(0);
        __syncthreads();
    }

    const int bb = hn >> 4, nn = hn & 15;
#pragma unroll
    for (int i = 0; i < 2; ++i) {
        float lt = l[i] + __shfl_xor(l[i], 16);
        lt += __shfl_xor(lt, 32);
        float inv = 1.0f / lt;
        const size_t rowoff = ((size_t)(bb * T_ + q0[i] + c0)) * D_ + nn * H_ + g * 4;
#pragma unroll
        for (int hf = 0; hf < 8; ++hf) {
            u16x4 pk;
#pragma unroll
            for (int r = 0; r < 4; ++r) pk[r] = f2bf(o[i][hf][r] * inv);
            *reinterpret_cast<u16x4*>(ob + rowoff + hf * 16) = pk;
        }
    }
}

// ---------------- launch ----------------
extern "C" void kernel_launch(void* const* d_in, const int* in_sizes, int n_in,
                              void* d_out, int out_size, void* d_ws, size_t ws_size,
                              hipStream_t stream) {
    const float* x      = (const float*)d_in[0];
    const float* cosT   = (const float*)d_in[2];
    const float* sinT   = (const float*)d_in[3];
    const float* w_attn = (const float*)d_in[4];
    const float* w_out  = (const float*)d_in[5];
    float* out = (float*)d_out;

    char* ws = (char*)d_ws;
    u16* xb  = (u16*)(ws + 0);
    u16* wat = (u16*)(ws + 16777216);
    u16* wot = (u16*)(ws + 41943040);
    u16* qkv = (u16*)(ws + 50331648);
    u16* qsb = (u16*)(ws + 100663296);
    u16* krb = (u16*)(ws + 117440512);
    u16* vtb = (u16*)(ws + 134217728);
    u16* obf = (u16*)(ws + 0);

    cvt_bf16<<<(B_ * T_ * D_) / (256 * 8), 256, 0, stream>>>(x, xb, B_ * T_ * D_);
    transpose_cvt<<<dim3(3 * D_ / 64, D_ / 64), 256, 0, stream>>>(w_attn, wat, D_, 3 * D_);
    transpose_cvt<<<dim3(D_ / 64, D_ / 64), 256, 0, stream>>>(w_out, wot, D_, D_);
    gemm_bt<<<dim3((3 * D_ / BN) * (B_ * T_ / BM)), 256, 0, stream>>>(xb, wat, qkv, nullptr,
                                                                      B_ * T_, 3 * D_, D_, 0);
    rope_split<<<B_ * N_ * (T_ / 64), 256, 0, stream>>>(qkv, cosT, sinT, qsb, krb, vtb);
    attn_fwd<<<B_ * N_ * (T_ / 128), 256, 0, stream>>>(qsb, krb, vtb, obf);
    gemm_bt<<<dim3((D_ / BN) * (B_ * T_ / BM)), 256, 0, stream>>>(obf, wot, nullptr, out,
                                                                  B_ * T_, D_, D_, 1);
}

// Round 12
// 309.818 us; speedup vs baseline: 1.1258x; 1.0176x over previous
//
#include <hip/hip_runtime.h>

typedef unsigned short u16;
typedef unsigned int u32;

#define B_ 2
#define T_ 2048
#define D_ 2048
#define N_ 16
#define H_ 128
#define F_ 64
// 1/sqrt(128) * log2(e)  -- log2e folded so softmax uses v_exp_f32 (2^x) directly
#define QSCALE 0.12751743226f

typedef __attribute__((ext_vector_type(8))) __bf16 bf16x8;
typedef __attribute__((ext_vector_type(8))) short s16x8;
typedef __attribute__((ext_vector_type(4))) float f32x4;
typedef __attribute__((ext_vector_type(4))) u16 u16x4;
typedef __attribute__((ext_vector_type(4))) u32 u32x4;

__device__ inline u16 f2bf(float f) {
    union { float f; u32 u; } v; v.f = f;
    u32 u = v.u;
    u32 r = (u + 0x7FFFu + ((u >> 16) & 1u)) >> 16;
    return (u16)r;
}
__device__ inline float bf2f(u16 h) {
    union { u32 u; float f; } v; v.u = ((u32)h) << 16;
    return v.f;
}
__device__ inline bf16x8 ld8(const u16* p) {
    s16x8 r = *reinterpret_cast<const s16x8*>(p);
    return __builtin_bit_cast(bf16x8, r);
}
__device__ inline f32x4 mfma16(bf16x8 a, bf16x8 b, f32x4 c) {
    return __builtin_amdgcn_mfma_f32_16x16x32_bf16(a, b, c, 0, 0, 0);
}
__device__ inline void gload_lds16(const u16* g, u16* l) {
    __builtin_amdgcn_global_load_lds(
        (const __attribute__((address_space(1))) void*)g,
        (__attribute__((address_space(3))) void*)l, 16, 0, 0);
}
__device__ inline float exp2fast(float x) {
    float r;
    asm("v_exp_f32 %0, %1" : "=v"(r) : "v"(x));
    return r;
}
__device__ inline u32 cvtpk(float lo, float hi) {
    u32 r;
    asm("v_cvt_pk_bf16_f32 %0, %1, %2" : "=v"(r) : "v"(lo), "v"(hi));
    return r;
}

// ---------------- merged prep: x cvt + w_attn transpose + w_out transpose ----------------
// Grid 8192: [0,4096) cvt x -> bf16; [4096,7168) transpose w_attn; [7168,8192) w_out.
// Bodies identical to the proven cvt_bf16 / transpose_cvt kernels; sections co-run,
// deleting 2 launch gaps and overlapping each section's fill/drain.
__global__ __launch_bounds__(256) void prep(const float* __restrict__ x,
                                            u16* __restrict__ xb,
                                            const float* __restrict__ wA,
                                            u16* __restrict__ wAt,
                                            const float* __restrict__ wO,
                                            u16* __restrict__ wOt) {
    __shared__ float tile[64][65];
    const int bid = blockIdx.x;
    const int tid = threadIdx.x;

    if (bid < 4096) {
        // ---- cvt x (f32 -> bf16), 2048 elems/block ----
        int i = (bid * 256 + tid) * 8;
        float4 a = *reinterpret_cast<const float4*>(x + i);
        float4 b = *reinterpret_cast<const float4*>(x + i + 4);
        s16x8 o;
        o[0] = (short)f2bf(a.x); o[1] = (short)f2bf(a.y);
        o[2] = (short)f2bf(a.z); o[3] = (short)f2bf(a.w);
        o[4] = (short)f2bf(b.x); o[5] = (short)f2bf(b.y);
        o[6] = (short)f2bf(b.z); o[7] = (short)f2bf(b.w);
        *reinterpret_cast<s16x8*>(xb + i) = o;
        return;
    }

    // ---- transpose+cvt section ----
    const float* in;
    u16* out;
    int Nc, bx, by;
    if (bid < 4096 + 3072) {
        int idx = bid - 4096;
        in = wA; out = wAt; Nc = 3 * D_;
        bx = idx % 96; by = idx / 96;
    } else {
        int idx = bid - 7168;
        in = wO; out = wOt; Nc = D_;
        bx = idx & 31; by = idx >> 5;
    }
    const int K = D_;
    int n0 = bx * 64, k0 = by * 64;
    int rr = tid >> 4;
    int cc = (tid & 15) * 4;
#pragma unroll
    for (int it = 0; it < 4; ++it) {
        int kk = it * 16 + rr;
        float4 v = *reinterpret_cast<const float4*>(in + (size_t)(k0 + kk) * Nc + n0 + cc);
        tile[kk][cc] = v.x; tile[kk][cc + 1] = v.y; tile[kk][cc + 2] = v.z; tile[kk][cc + 3] = v.w;
    }
    __syncthreads();
#pragma unroll
    for (int it = 0; it < 4; ++it) {
        int nn = it * 16 + rr;
        u16x4 o;
#pragma unroll
        for (int j = 0; j < 4; ++j) o[j] = f2bf(tile[cc + j][nn]);
        *reinterpret_cast<u16x4*>(out + (size_t)(n0 + nn) * K + k0 + cc) = o;
    }
}

// ---------------- 128x128 GEMM (both projections), XCD-rect swizzle ----------------
#define BM 128
#define BN 128
#define BKg 32

__global__ __launch_bounds__(256) void gemm_bt(const u16* __restrict__ A,
                                               const u16* __restrict__ Bt,
                                               u16* __restrict__ Cb,
                                               float* __restrict__ Cf,
                                               int M, int Nn, int K, int out_f32) {
    __shared__ __align__(16) u16 As[2][BM * BKg];
    __shared__ __align__(16) u16 Bs[2][BM * BKg];
    const int tid = threadIdx.x;
    const int wave = tid >> 6, lane = tid & 63;

    const int NW = (Nn >> 7) >> 3;          // n-tiles per XCD
    const int bid = blockIdx.x;
    const int xcd = bid & 7, idx = bid >> 3;
    const int nloc = idx % NW, mloc = idx / NW;
    const int m0 = mloc * BM, n0 = (xcd * NW + nloc) * BN;

    const int lrow = lane >> 2, lcol = (lane & 3) * 8;
    const int wr = (wave >> 1) * 64, wc = (wave & 1) * 64;
    const int g = lane >> 4, c0 = lane & 15;

    f32x4 acc[4][4] = {};

    const int NT = K / BKg;

    auto stage = [&](int buf, int kt) {
        const int k0 = kt * BKg;
#pragma unroll
        for (int j = 0; j < 2; ++j) {
            const int c = wave + j * 4;
            gload_lds16(A + (size_t)(m0 + c * 16 + lrow) * K + k0 + lcol, &As[buf][c * 512]);
            gload_lds16(Bt + (size_t)(n0 + c * 16 + lrow) * K + k0 + lcol, &Bs[buf][c * 512]);
        }
    };

    stage(0, 0);
    __syncthreads();

    for (int t = 0; t < NT; ++t) {
        const int cur = t & 1;
        if (t + 1 < NT) stage(cur ^ 1, t + 1);
        bf16x8 af[4], bfr[4];
#pragma unroll
        for (int i = 0; i < 4; ++i) {
            af[i]  = ld8(&As[cur][(wr + i * 16 + c0) * BKg + g * 8]);
            bfr[i] = ld8(&Bs[cur][(wc + i * 16 + c0) * BKg + g * 8]);
        }
#pragma unroll
        for (int i = 0; i < 4; ++i)
#pragma unroll
            for (int j = 0; j < 4; ++j)
                acc[i][j] = mfma16(af[i], bfr[j], acc[i][j]);
        __syncthreads();
    }

#pragma unroll
    for (int i = 0; i < 4; ++i)
#pragma unroll
        for (int j = 0; j < 4; ++j)
#pragma unroll
            for (int r = 0; r < 4; ++r) {
                int row = m0 + wr + i * 16 + g * 4 + r;
                int col = n0 + wc + j * 16 + c0;
                float v = acc[i][j][r];
                if (out_f32) Cf[(size_t)row * Nn + col] = v;
                else         Cb[(size_t)row * Nn + col] = f2bf(v);
            }
}

// ---------------- RoPE + head-split + V-transpose ----------------
__global__ __launch_bounds__(256) void rope_split(const u16* __restrict__ qkv,
                                                  const float* __restrict__ cosT,
                                                  const float* __restrict__ sinT,
                                                  u16* __restrict__ qs,
                                                  u16* __restrict__ kr,
                                                  u16* __restrict__ vt) {
    __shared__ u16 vtile[64][129];
    int bi = blockIdx.x;
    int hn = bi >> 5;
    int tt = bi & 31;
    int b = hn >> 4, n = hn & 15;
    int t0 = tt * 64;
    int tid = threadIdx.x;
    int tl = tid >> 2;
    int h0 = (tid & 3) * 32;
    int t = t0 + tl;
    const u16* row = qkv + ((size_t)(b * T_ + t)) * (3 * D_);

#pragma unroll
    for (int u = 0; u < 4; ++u) {
        s16x8 raw = *reinterpret_cast<const s16x8*>(row + n * H_ + h0 + u * 8);
        s16x8 o;
#pragma unroll
        for (int e = 0; e < 8; ++e) o[e] = (short)f2bf(bf2f((u16)raw[e]) * QSCALE);
        *reinterpret_cast<s16x8*>(qs + ((size_t)hn * T_ + t) * H_ + h0 + u * 8) = o;
    }

    float cbuf[16], sbuf[16];
    const float* cr = cosT + (size_t)t * F_ + h0 / 2;
    const float* sr = sinT + (size_t)t * F_ + h0 / 2;
#pragma unroll
    for (int u = 0; u < 4; ++u) {
        float4 c4 = *reinterpret_cast<const float4*>(cr + u * 4);
        float4 s4 = *reinterpret_cast<const float4*>(sr + u * 4);
        cbuf[u * 4 + 0] = c4.x; cbuf[u * 4 + 1] = c4.y; cbuf[u * 4 + 2] = c4.z; cbuf[u * 4 + 3] = c4.w;
        sbuf[u * 4 + 0] = s4.x; sbuf[u * 4 + 1] = s4.y; sbuf[u * 4 + 2] = s4.z; sbuf[u * 4 + 3] = s4.w;
    }

#pragma unroll
    for (int u = 0; u < 4; ++u) {
        s16x8 raw = *reinterpret_cast<const s16x8*>(row + D_ + n * H_ + h0 + u * 8);
        s16x8 o;
#pragma unroll
        for (int p = 0; p < 4; ++p) {
            float xr = bf2f((u16)raw[2 * p]), xi = bf2f((u16)raw[2 * p + 1]);
            float cc = cbuf[u * 4 + p], ss = sbuf[u * 4 + p];
            o[2 * p]     = (short)f2bf(xr * cc - xi * ss);
            o[2 * p + 1] = (short)f2bf(xr * ss + xi * cc);
        }
        *reinterpret_cast<s16x8*>(kr + ((size_t)hn * T_ + t) * H_ + h0 + u * 8) = o;
    }

#pragma unroll
    for (int u = 0; u < 4; ++u) {
        s16x8 raw = *reinterpret_cast<const s16x8*>(row + 2 * D_ + n * H_ + h0 + u * 8);
#pragma unroll
        for (int p = 0; p < 4; ++p) {
            float xr = bf2f((u16)raw[2 * p]), xi = bf2f((u16)raw[2 * p + 1]);
            float cc = cbuf[u * 4 + p], ss = sbuf[u * 4 + p];
            vtile[tl][h0 + u * 8 + 2 * p]     = f2bf(xr * cc - xi * ss);
            vtile[tl][h0 + u * 8 + 2 * p + 1] = f2bf(xr * ss + xi * cc);
        }
    }
    __syncthreads();

    int hrow = tid >> 1;
    int th = (tid & 1) * 32;
    u16 tmp[32];
#pragma unroll
    for (int i = 0; i < 32; ++i) tmp[i] = vtile[th + i][hrow];
    u16* dst = vt + ((size_t)(hn * H_ + hrow)) * T_ + t0 + th;
#pragma unroll
    for (int u = 0; u < 4; ++u) {
        s16x8 o;
#pragma unroll
        for (int e = 0; e < 8; ++e) o[e] = (short)tmp[u * 8 + e];
        *reinterpret_cast<s16x8*>(dst + u * 8) = o;
    }
}

// ---------------- flash attention (causal), swapped-operand softmax ----------------
// Round-11 structure (proven + balanced): paired complementary halves per block.
__global__ __launch_bounds__(256, 2) void attn_fwd(const u16* __restrict__ qs,
                                                   const u16* __restrict__ kr,
                                                   const u16* __restrict__ vt,
                                                   u16* __restrict__ ob) {
    __shared__ __align__(16) u16 Ks[2][8192];
    __shared__ __align__(16) u16 Vs[2][8192];

    const int wave = threadIdx.x >> 6, lane = threadIdx.x & 63;
    const int g = lane >> 4, c0 = lane & 15;

    const int wg = blockIdx.x;
    const int orig = (wg & 7) * 64 + (wg >> 3);
    const int hn = orig >> 4;
    const int qt = orig & 15;
    const int hA = 31 - qt;      // long 64-row half
    const int hB = qt;           // complementary short half

    const u16* qh = qs + (size_t)hn * T_ * H_;
    const u16* kh = kr + (size_t)hn * T_ * H_;
    const u16* vh = vt + (size_t)hn * H_ * T_;

    const int q0[2] = { hA * 64 + wave * 16, hB * 64 + wave * 16 };

    bf16x8 qf[2][4];
#pragma unroll
    for (int i = 0; i < 2; ++i)
#pragma unroll
        for (int kf = 0; kf < 4; ++kf)
            qf[i][kf] = ld8(qh + (size_t)(q0[i] + c0) * H_ + kf * 32 + g * 8);

    f32x4 o[2][8] = {};
    float m[2] = { -1e30f, -1e30f };
    float l[2] = { 0.0f, 0.0f };

    const int nt = hA + 1;

    auto stage = [&](int buf, int t) {
        const int kv0 = t * 64;
#pragma unroll
        for (int j = 0; j < 4; ++j) {
            int ra = wave * 16 + j * 4 + (lane >> 4);
            int ca = ((lane & 15) * 8) ^ ((ra & 7) << 3);
            gload_lds16(kh + (size_t)(kv0 + ra) * H_ + ca, &Ks[buf][wave * 2048 + j * 512]);
            int rv = wave * 32 + j * 8 + (lane >> 3);
            int cv = ((lane & 7) * 8) ^ ((rv & 7) << 3);
            gload_lds16(vh + (size_t)rv * T_ + kv0 + cv, &Vs[buf][wave * 2048 + j * 512]);
        }
    };

    stage(0, 0);
    __syncthreads();

    const int srcA = ((g & 1) * 2) * 16 + c0;
    const int srcB = srcA + 16;
    const int sel  = g >> 1;

    for (int t = 0; t < nt; ++t) {
        const int cur = t & 1;
        const int kv0 = t * 64;
        if (t + 1 < nt) stage(cur ^ 1, t + 1);

        const bool a0 = kv0 < q0[0] + 16;
        const bool a1 = kv0 < q0[1] + 16;

        f32x4 s[2][4] = {};
        __builtin_amdgcn_s_setprio(1);
#pragma unroll
        for (int cc = 0; cc < 4; ++cc) {
            const int krow = cc * 16 + c0;
#pragma unroll
            for (int kf = 0; kf < 4; ++kf) {
                bf16x8 kfr = ld8(&Ks[cur][krow * 128 + ((kf * 32 + g * 8) ^ ((krow & 7) << 3))]);
                if (a0) s[0][cc] = mfma16(kfr, qf[0][kf], s[0][cc]);
                if (a1) s[1][cc] = mfma16(kfr, qf[1][kf], s[1][cc]);
            }
        }
        __builtin_amdgcn_s_setprio(0);

        bf16x8 pb[2][2];
#pragma unroll
        for (int i = 0; i < 2; ++i) {
            const bool act = i ? a1 : a0;
            if (!act) continue;
            const int qrow = q0[i] + c0;
            if (kv0 + 63 > q0[i]) {
#pragma unroll
                for (int cc = 0; cc < 4; ++cc) {
                    int kloc = kv0 + cc * 16 + g * 4;
#pragma unroll
                    for (int r = 0; r < 4; ++r)
                        if (kloc + r > qrow) s[i][cc][r] = -1e30f;
                }
            }
            float pmax = s[i][0][0];
#pragma unroll
            for (int cc = 0; cc < 4; ++cc)
#pragma unroll
                for (int r = 0; r < 4; ++r) pmax = fmaxf(pmax, s[i][cc][r]);
            if (!__all(pmax <= m[i] + 8.0f)) {
                pmax = fmaxf(pmax, __shfl_xor(pmax, 16));
                pmax = fmaxf(pmax, __shfl_xor(pmax, 32));
                float mn = fmaxf(m[i], pmax);
                float al = exp2fast(m[i] - mn);
                m[i] = mn;
                l[i] *= al;
#pragma unroll
                for (int hf = 0; hf < 8; ++hf)
#pragma unroll
                    for (int r = 0; r < 4; ++r) o[i][hf][r] *= al;
            }
            u32 w[4][2];
#pragma unroll
            for (int cc = 0; cc < 4; ++cc) {
                float p0 = exp2fast(s[i][cc][0] - m[i]);
                float p1 = exp2fast(s[i][cc][1] - m[i]);
                float p2 = exp2fast(s[i][cc][2] - m[i]);
                float p3 = exp2fast(s[i][cc][3] - m[i]);
                l[i] += (p0 + p1) + (p2 + p3);
                w[cc][0] = cvtpk(p0, p1);
                w[cc][1] = cvtpk(p2, p3);
            }
#pragma unroll
            for (int ks2 = 0; ks2 < 2; ++ks2) {
                u32 r00 = __shfl(w[ks2 * 2 + 0][0], srcA);
                u32 r01 = __shfl(w[ks2 * 2 + 0][1], srcA);
                u32 r02 = __shfl(w[ks2 * 2 + 0][0], srcB);
                u32 r03 = __shfl(w[ks2 * 2 + 0][1], srcB);
                u32 r10 = __shfl(w[ks2 * 2 + 1][0], srcA);
                u32 r11 = __shfl(w[ks2 * 2 + 1][1], srcA);
                u32 r12 = __shfl(w[ks2 * 2 + 1][0], srcB);
                u32 r13 = __shfl(w[ks2 * 2 + 1][1], srcB);
                u32x4 wv;
                wv[0] = sel ? r10 : r00;
                wv[1] = sel ? r11 : r01;
                wv[2] = sel ? r12 : r02;
                wv[3] = sel ? r13 : r03;
                pb[i][ks2] = __builtin_bit_cast(bf16x8, wv);
            }
        }

        __builtin_amdgcn_s_setprio(1);
#pragma unroll
        for (int hf = 0; hf < 8; ++hf) {
            const int vrow = hf * 16 + c0;
#pragma unroll
            for (int ks2 = 0; ks2 < 2; ++ks2) {
                bf16x8 vfr = ld8(&Vs[cur][vrow * 64 + ((ks2 * 32 + g * 8) ^ ((vrow & 7) << 3))]);
                if (a0) o[0][hf] = mfma16(vfr, pb[0][ks2], o[0][hf]);
                if (a1) o[1][hf] = mfma16(vfr, pb[1][ks2], o[1][hf]);
            }
        }
        __builtin_amdgcn_s_setprio(0);
        __syncthreads();
    }

    const int bb = hn >> 4, nn = hn & 15;
#pragma unroll
    for (int i = 0; i < 2; ++i) {
        float lt = l[i] + __shfl_xor(l[i], 16);
        lt += __shfl_xor(lt, 32);
        float inv = 1.0f / lt;
        const size_t rowoff = ((size_t)(bb * T_ + q0[i] + c0)) * D_ + nn * H_ + g * 4;
#pragma unroll
        for (int hf = 0; hf < 8; ++hf) {
            u16x4 pk;
#pragma unroll
            for (int r = 0; r < 4; ++r) pk[r] = f2bf(o[i][hf][r] * inv);
            *reinterpret_cast<u16x4*>(ob + rowoff + hf * 16) = pk;
        }
    }
}

// ---------------- launch ----------------
extern "C" void kernel_launch(void* const* d_in, const int* in_sizes, int n_in,
                              void* d_out, int out_size, void* d_ws, size_t ws_size,
                              hipStream_t stream) {
    const float* x      = (const float*)d_in[0];
    const float* cosT   = (const float*)d_in[2];
    const float* sinT   = (const float*)d_in[3];
    const float* w_attn = (const float*)d_in[4];
    const float* w_out  = (const float*)d_in[5];
    float* out = (float*)d_out;

    char* ws = (char*)d_ws;
    u16* xb  = (u16*)(ws + 0);
    u16* wat = (u16*)(ws + 16777216);
    u16* wot = (u16*)(ws + 41943040);
    u16* qkv = (u16*)(ws + 50331648);
    u16* qsb = (u16*)(ws + 100663296);
    u16* krb = (u16*)(ws + 117440512);
    u16* vtb = (u16*)(ws + 134217728);
    u16* obf = (u16*)(ws + 0);

    prep<<<8192, 256, 0, stream>>>(x, xb, w_attn, wat, w_out, wot);
    gemm_bt<<<dim3((3 * D_ / BN) * (B_ * T_ / BM)), 256, 0, stream>>>(xb, wat, qkv, nullptr,
                                                                      B_ * T_, 3 * D_, D_, 0);
    rope_split<<<B_ * N_ * (T_ / 64), 256, 0, stream>>>(qkv, cosT, sinT, qsb, krb, vtb);
    attn_fwd<<<B_ * N_ * (T_ / 128), 256, 0, stream>>>(qsb, krb, vtb, obf);
    gemm_bt<<<dim3((D_ / BN) * (B_ * T_ / BM)), 256, 0, stream>>>(obf, wot, nullptr, out,
                                                                  B_ * T_, D_, D_, 1);
}